// Round 1
// baseline (513.366 us; speedup 1.0000x reference)
//
#include <hip/hip_runtime.h>
#include <type_traits>

#define LMAX 24

// ---------- compile-time normalization table K(l,m) ----------
constexpr double csqrt_(double x) {
  double y = x > 1.0 ? x : 1.0;
  for (int i = 0; i < 300; ++i) y = 0.5 * (y + x / y);
  return y;
}
constexpr double cfact_(int n) {
  double r = 1.0;
  for (int i = 2; i <= n; ++i) r *= (double)i;
  return r;
}
constexpr double PI_ = 3.14159265358979323846;

struct KTab {
  float k[LMAX][LMAX];
  constexpr KTab() : k{} {
    for (int l = 0; l < LMAX; ++l)
      for (int m = 0; m <= l; ++m)
        k[l][m] = (float)csqrt_((2.0 * l + 1.0) * cfact_(l - m) /
                                (4.0 * PI_ * cfact_(l + m)));
  }
};
constexpr KTab KT{};
constexpr float SQRT2_ = 1.41421356237309504880f;

// ---------- compile-time loop unroller (guarantees constant indices) ----------
template <int N, int I = 0, typename F>
__device__ __forceinline__ void static_for(F&& f) {
  if constexpr (I < N) {
    f(std::integral_constant<int, I>{});
    static_for<N, I + 1>(f);
  }
}

__global__ __launch_bounds__(256) void sh_kernel(const float* __restrict__ rd,
                                                 float* __restrict__ out, int n) {
  int i = blockIdx.x * 256 + threadIdx.x;
  if (i >= n) return;

  const float2 p = reinterpret_cast<const float2*>(rd)[i];
  const float D2R = 0.017453292519943295f;
  float phi = p.x * D2R;
  float theta = (p.y + 90.0f) * D2R;
  float x = cosf(theta);
  float somx2 = sqrtf((1.0f - x) * (1.0f + x));

  // cos(m*phi), sin(m*phi) via Chebyshev recurrence (register arrays)
  float cm[LMAX], sm[LMAX];
  cm[0] = 1.0f; sm[0] = 0.0f;
  float c1 = cosf(phi), s1 = sinf(phi);
  cm[1] = c1; sm[1] = s1;
  float twoc = 2.0f * c1;
#pragma unroll
  for (int m = 2; m < LMAX; ++m) {
    cm[m] = twoc * cm[m - 1] - cm[m - 2];
    sm[m] = twoc * sm[m - 1] - sm[m - 2];
  }

  float cur[LMAX], prev[LMAX];
  float pmm = 1.0f;
  float buf[4];
  float* row = out + (size_t)i * (LMAX * LMAX);

  static_for<LMAX>([&](auto LC) {
    constexpr int l = decltype(LC)::value;

    // advance recurrence state for all m < l  (gives P(l,m))
    static_for<l>([&](auto MC) {
      constexpr int m = decltype(MC)::value;
      constexpr float a = (float)(2 * l - 1);
      constexpr float b = (float)(l + m - 1);
      constexpr float inv = 1.0f / (float)(l - m);
      float nxt = (a * x * cur[m] - b * prev[m]) * inv;
      prev[m] = cur[m];
      cur[m] = nxt;
    });

    // init state for m = l:  P(l,l) = pmm,  prev = 0 (makes the unified
    // recurrence reproduce P[m+1,m] = (2m+1)*x*pmm at the next step)
    if constexpr (l > 0) {
      pmm = pmm * (-(float)(2 * l - 1)) * somx2;
    }
    cur[l] = pmm;
    prev[l] = 0.0f;

    // emit row l in j order: m = -l .. l  (j = l*l + l + m is contiguous
    // across the whole kernel: 0..575), flush as aligned float4
    static_for<2 * l + 1>([&](auto KC) {
      constexpr int m = decltype(KC)::value - l;
      constexpr int am = m < 0 ? -m : m;
      constexpr int j = l * l + l + m;
      constexpr float C = (m == 0) ? KT.k[l][0] : SQRT2_ * KT.k[l][am];
      float y;
      if constexpr (m == 0) {
        y = C * cur[0];
      } else if constexpr (m > 0) {
        y = C * (cm[am] * cur[am]);
      } else {
        y = C * (sm[am] * cur[am]);
      }
      buf[j & 3] = y;
      if constexpr ((j & 3) == 3) {
        *reinterpret_cast<float4*>(row + (j - 3)) =
            make_float4(buf[0], buf[1], buf[2], buf[3]);
      }
    });
  });
}

extern "C" void kernel_launch(void* const* d_in, const int* in_sizes, int n_in,
                              void* d_out, int out_size, void* d_ws, size_t ws_size,
                              hipStream_t stream) {
  (void)n_in; (void)out_size; (void)d_ws; (void)ws_size;
  const float* rd = (const float*)d_in[0];
  float* out = (float*)d_out;
  int n = in_sizes[0] / 2;
  int grid = (n + 255) / 256;
  sh_kernel<<<grid, 256, 0, stream>>>(rd, out, n);
}

// Round 2
// 187.947 us; speedup vs baseline: 2.7314x; 2.7314x over previous
//
#include <hip/hip_runtime.h>
#include <type_traits>

#define LMAX 24

// ---------- compile-time normalization table K(l,m) ----------
constexpr double csqrt_(double x) {
  double y = x > 1.0 ? x : 1.0;
  for (int i = 0; i < 300; ++i) y = 0.5 * (y + x / y);
  return y;
}
constexpr double cfact_(int n) {
  double r = 1.0;
  for (int i = 2; i <= n; ++i) r *= (double)i;
  return r;
}
constexpr double PI_ = 3.14159265358979323846;

struct KTab {
  float k[LMAX][LMAX];
  constexpr KTab() : k{} {
    for (int l = 0; l < LMAX; ++l)
      for (int m = 0; m <= l; ++m)
        k[l][m] = (float)csqrt_((2.0 * l + 1.0) * cfact_(l - m) /
                                (4.0 * PI_ * cfact_(l + m)));
  }
};
constexpr KTab KT{};
constexpr float SQRT2_ = 1.41421356237309504880f;

// ---------- compile-time loop unroller ----------
template <int N, int I = 0, typename F>
__device__ __forceinline__ void static_for(F&& f) {
  if constexpr (I < N) {
    f(std::integral_constant<int, I>{});
    static_for<N, I + 1>(f);
  }
}

// Per-wave staging: [64 points][32 j-values], row stride 33 dwords.
// Write bank = (lane + j) % 32  -> 2-way (free).
// Flush reads bank = (8t + r + 4c + k) % 32 -> uniform 2-way (free).
#define CJ 32
#define STR 33

__global__ __launch_bounds__(256) void sh_kernel(const float* __restrict__ rd,
                                                 float* __restrict__ out, int n) {
  __shared__ float lds[4 * 64 * STR];

  const int tid = threadIdx.x;
  const int wave = tid >> 6;
  const int lane = tid & 63;
  const long long base_pt = (long long)blockIdx.x * 256 + wave * 64;
  const long long my_pt = base_pt + lane;
  const int src = my_pt < n ? (int)my_pt : 0;

  const float2 p = reinterpret_cast<const float2*>(rd)[src];
  const float D2R = 0.017453292519943295f;
  float phi = p.x * D2R;
  float theta = (p.y + 90.0f) * D2R;
  float x = cosf(theta);
  float somx2 = sqrtf((1.0f - x) * (1.0f + x));

  // cos(m*phi), sin(m*phi) via Chebyshev recurrence (register arrays)
  float cm[LMAX], sm[LMAX];
  cm[0] = 1.0f; sm[0] = 0.0f;
  float c1 = cosf(phi), s1 = sinf(phi);
  cm[1] = c1; sm[1] = s1;
  float twoc = 2.0f * c1;
#pragma unroll
  for (int m = 2; m < LMAX; ++m) {
    cm[m] = twoc * cm[m - 1] - cm[m - 2];
    sm[m] = twoc * sm[m - 1] - sm[m - 2];
  }

  float cur[LMAX], prev[LMAX];
  float pmm = 1.0f;

  float* const wptr = lds + wave * (64 * STR) + lane * STR;   // this thread's row
  const float* const rbase = lds + wave * (64 * STR);          // wave's buffer

  // cooperative flush of chunk jc (32 j-values for all 64 points of the wave)
  auto flush = [&](int jc) {
    __builtin_amdgcn_wave_barrier();
#pragma unroll
    for (int t = 0; t < 8; ++t) {
      int pp = t * 8 + (lane >> 3);            // point within wave
      int off = pp * STR + (lane & 7) * 4;     // dword offset in LDS
      float4 v = make_float4(rbase[off], rbase[off + 1],
                             rbase[off + 2], rbase[off + 3]);
      long long pt = base_pt + pp;
      if (pt < n) {
        *reinterpret_cast<float4*>(out + (size_t)pt * (LMAX * LMAX) +
                                   jc * CJ + (lane & 7) * 4) = v;
      }
    }
    __builtin_amdgcn_wave_barrier();
  };

  static_for<LMAX>([&](auto LC) {
    constexpr int l = decltype(LC)::value;

    // advance recurrence state for all m < l  (gives P(l,m))
    static_for<l>([&](auto MC) {
      constexpr int m = decltype(MC)::value;
      constexpr float a = (float)(2 * l - 1);
      constexpr float b = (float)(l + m - 1);
      constexpr float inv = 1.0f / (float)(l - m);
      float nxt = (a * x * cur[m] - b * prev[m]) * inv;
      prev[m] = cur[m];
      cur[m] = nxt;
    });

    // init state for m = l:  P(l,l) = pmm,  prev = 0
    if constexpr (l > 0) {
      pmm = pmm * (-(float)(2 * l - 1)) * somx2;
    }
    cur[l] = pmm;
    prev[l] = 0.0f;

    // emit row l in j order (j = l*l + l + m, globally contiguous 0..575),
    // staging into LDS; flush every 32 values
    static_for<2 * l + 1>([&](auto KC) {
      constexpr int m = decltype(KC)::value - l;
      constexpr int am = m < 0 ? -m : m;
      constexpr int j = l * l + l + m;
      constexpr float C = (m == 0) ? KT.k[l][0] : SQRT2_ * KT.k[l][am];
      float y;
      if constexpr (m == 0) {
        y = C * cur[0];
      } else if constexpr (m > 0) {
        y = C * (cm[am] * cur[am]);
      } else {
        y = C * (sm[am] * cur[am]);
      }
      wptr[j & (CJ - 1)] = y;
      if constexpr ((j & (CJ - 1)) == CJ - 1) {
        flush(j >> 5);
      }
    });
  });
}

extern "C" void kernel_launch(void* const* d_in, const int* in_sizes, int n_in,
                              void* d_out, int out_size, void* d_ws, size_t ws_size,
                              hipStream_t stream) {
  (void)n_in; (void)out_size; (void)d_ws; (void)ws_size;
  const float* rd = (const float*)d_in[0];
  float* out = (float*)d_out;
  int n = in_sizes[0] / 2;
  int grid = (n + 255) / 256;
  sh_kernel<<<grid, 256, 0, stream>>>(rd, out, n);
}